// Round 1
// baseline (360.311 us; speedup 1.0000x reference)
//
#include <hip/hip_runtime.h>

// Factorial HMM forward (3 chains x 8 states = 512 states, M=4, T=65536).
// Strategy: probability-domain scaled forward recurrence; transition applied as
// three 8x8 tensor contractions (chain-0 in-lane, chains 1/2 cross-lane via
// ds_bpermute). Chunked-parallel over T with burn-in (filter forgetting).
// One wave (64 lanes) per chunk; lane l holds states s = r*64 + l, r=0..7.

#define NCHUNK 1024
#define CLEN   64          // NCHUNK * CLEN == 65536
#define BURN   128

__device__ __forceinline__ float wave_reduce_max(float v) {
#pragma unroll
  for (int m = 32; m >= 1; m >>= 1) v = fmaxf(v, __shfl_xor(v, m, 64));
  return v;
}
__device__ __forceinline__ float wave_reduce_sum(float v) {
#pragma unroll
  for (int m = 32; m >= 1; m >>= 1) v += __shfl_xor(v, m, 64);
  return v;
}

__global__ __launch_bounds__(64, 1)
void hmm_fwd_chunk(const int* __restrict__ x,
                   const float* __restrict__ lam0, const float* __restrict__ lam1,
                   const float* __restrict__ lam2,
                   const float* __restrict__ logA0, const float* __restrict__ logA1,
                   const float* __restrict__ logA2,
                   const float* __restrict__ logp0, const float* __restrict__ logp1,
                   const float* __restrict__ logp2,
                   double* __restrict__ accum)
{
  const int l = threadIdx.x;        // 0..63
  const int chunk = blockIdx.x;     // 0..NCHUNK-1
  const int j1 = l >> 3;            // chain-1 state of this lane
  const int j2 = l & 7;             // chain-2 state of this lane

  // log(n!) table for n = x in [0,19]  (lgamma(x+1))
  __shared__ float lgam[20];
  if (l == 0) {
    lgam[0]  = 0.0f;          lgam[1]  = 0.0f;
    lgam[2]  = 0.69314718f;   lgam[3]  = 1.79175947f;
    lgam[4]  = 3.17805383f;   lgam[5]  = 4.78749174f;
    lgam[6]  = 6.57925121f;   lgam[7]  = 8.52516136f;
    lgam[8]  = 10.60460290f;  lgam[9]  = 12.80182748f;
    lgam[10] = 15.10441257f;  lgam[11] = 17.50230785f;
    lgam[12] = 19.98721450f;  lgam[13] = 22.55216385f;
    lgam[14] = 25.19122118f;  lgam[15] = 27.89927138f;
    lgam[16] = 30.67186011f;  lgam[17] = 33.50507345f;
    lgam[18] = 36.39544521f;  lgam[19] = 39.33988419f;
  }
  __syncthreads();

  // ---- transition probability tables: T = exp(log_softmax(logA, axis=0)) ----
  // Chain 0: full 8x8, lane-uniform (contracted in-lane over registers).
  float T0f[8][8];
#pragma unroll
  for (int k = 0; k < 8; ++k) {
    float m = logA0[k];
#pragma unroll
    for (int j = 1; j < 8; ++j) m = fmaxf(m, logA0[j * 8 + k]);
    float s = 0.f;
#pragma unroll
    for (int j = 0; j < 8; ++j) s += __expf(logA0[j * 8 + k] - m);
    float inv = 1.0f / s;
#pragma unroll
    for (int j = 0; j < 8; ++j) T0f[j][k] = __expf(logA0[j * 8 + k] - m) * inv;
  }
  // Chain 1: lane keeps only its output row T1[j1, k].
  float T1r[8];
#pragma unroll
  for (int k = 0; k < 8; ++k) {
    float m = logA1[k];
#pragma unroll
    for (int j = 1; j < 8; ++j) m = fmaxf(m, logA1[j * 8 + k]);
    float s = 0.f;
#pragma unroll
    for (int j = 0; j < 8; ++j) s += __expf(logA1[j * 8 + k] - m);
    T1r[k] = __expf(logA1[j1 * 8 + k] - m) / s;
  }
  // Chain 2: lane keeps row T2[j2, k].
  float T2r[8];
#pragma unroll
  for (int k = 0; k < 8; ++k) {
    float m = logA2[k];
#pragma unroll
    for (int j = 1; j < 8; ++j) m = fmaxf(m, logA2[j * 8 + k]);
    float s = 0.f;
#pragma unroll
    for (int j = 0; j < 8; ++j) s += __expf(logA2[j * 8 + k] - m);
    T2r[k] = __expf(logA2[j2 * 8 + k] - m) / s;
  }

  // ---- emission tables: lambdaC and log(lambdaC) for this lane's 8 states ----
  float Lt[8][4], sumLam[8];
#pragma unroll
  for (int r = 0; r < 8; ++r) {
    float s = 0.f;
#pragma unroll
    for (int m = 0; m < 4; ++m) {
      float lam = lam0[r * 4 + m] + lam1[j1 * 4 + m] + lam2[j2 * 4 + m];
      Lt[r][m] = __logf(lam);
      s += lam;
    }
    sumLam[r] = s;
  }

  // bpermute byte addresses (loop-invariant)
  int a1[8], a2[8];
#pragma unroll
  for (int k = 0; k < 8; ++k) {
    a1[k] = (k * 8 + j2) << 2;   // gather over k1 (keep k2)
    a2[k] = (j1 * 8 + k) << 2;   // gather over k2 (keep j1)
  }

  const int tstart = chunk * CLEN;
  const int tend = tstart + CLEN;

  float v[8];
  double zacc = 0.0;
  int t;

  // emission log-prob (incl. -C_t) for all 8 register states
  auto emis = [&](const int4 xi, float e[8]) {
    const float xf0 = (float)xi.x, xf1 = (float)xi.y,
                xf2 = (float)xi.z, xf3 = (float)xi.w;
    const float Ct = lgam[xi.x] + lgam[xi.y] + lgam[xi.z] + lgam[xi.w];
#pragma unroll
    for (int r = 0; r < 8; ++r) {
      float a = -sumLam[r] - Ct;
      a = fmaf(xf0, Lt[r][0], a);
      a = fmaf(xf1, Lt[r][1], a);
      a = fmaf(xf2, Lt[r][2], a);
      a = fmaf(xf3, Lt[r][3], a);
      e[r] = a;
    }
  };

  if (chunk == 0) {
    // exact init from prior at t=0
    float lp0[8];
    {
      float m = logp0[0];
#pragma unroll
      for (int j = 1; j < 8; ++j) m = fmaxf(m, logp0[j]);
      float s = 0.f;
#pragma unroll
      for (int j = 0; j < 8; ++j) s += __expf(logp0[j] - m);
      float lg = m + __logf(s);
#pragma unroll
      for (int j = 0; j < 8; ++j) lp0[j] = logp0[j] - lg;
    }
    float lp1v, lp2v;
    {
      float m = logp1[0];
#pragma unroll
      for (int j = 1; j < 8; ++j) m = fmaxf(m, logp1[j]);
      float s = 0.f;
#pragma unroll
      for (int j = 0; j < 8; ++j) s += __expf(logp1[j] - m);
      lp1v = logp1[j1] - (m + __logf(s));
    }
    {
      float m = logp2[0];
#pragma unroll
      for (int j = 1; j < 8; ++j) m = fmaxf(m, logp2[j]);
      float s = 0.f;
#pragma unroll
      for (int j = 0; j < 8; ++j) s += __expf(logp2[j] - m);
      lp2v = logp2[j2] - (m + __logf(s));
    }
    float e[8];
    emis(*reinterpret_cast<const int4*>(x), e);
    float a[8];
    float mx = -3.0e38f;
#pragma unroll
    for (int r = 0; r < 8; ++r) {
      a[r] = lp0[r] + lp1v + lp2v + e[r];
      mx = fmaxf(mx, a[r]);
    }
    mx = wave_reduce_max(mx);
#pragma unroll
    for (int r = 0; r < 8; ++r) v[r] = __expf(a[r] - mx);
    zacc = (double)mx;
    t = 1;
  } else {
    // burn-in from a uniform (unnormalized) message
#pragma unroll
    for (int r = 0; r < 8; ++r) v[r] = 1.0f;
    t = tstart - BURN;
    if (t < 0) t = 0;
  }

  auto step = [&](int tt, bool accumulate) {
    const int4 xi = *reinterpret_cast<const int4*>(x + 4 * tt);
    float e[8];
    emis(xi, e);

    // ---- chain-0 contraction (in-lane over registers) ----
    float q[8];
#pragma unroll
    for (int j = 0; j < 8; ++j) {
      float a = T0f[j][0] * v[0];
#pragma unroll
      for (int k = 1; k < 8; ++k) a = fmaf(T0f[j][k], v[k], a);
      q[j] = a;
    }
    // ---- chain-1 contraction (cross-lane, lane bits 3..5) ----
#pragma unroll
    for (int j = 0; j < 8; ++j) {
      float a = 0.f;
#pragma unroll
      for (int k = 0; k < 8; ++k) {
        float g = __int_as_float(
            __builtin_amdgcn_ds_bpermute(a1[k], __float_as_int(q[j])));
        a = fmaf(T1r[k], g, a);
      }
      q[j] = a;
    }
    // ---- chain-2 contraction (cross-lane, lane bits 0..2) ----
#pragma unroll
    for (int j = 0; j < 8; ++j) {
      float a = 0.f;
#pragma unroll
      for (int k = 0; k < 8; ++k) {
        float g = __int_as_float(
            __builtin_amdgcn_ds_bpermute(a2[k], __float_as_int(q[j])));
        a = fmaf(T2r[k], g, a);
      }
      q[j] = a;
    }

    // ---- emission multiply with max-shift (range safety), then renormalize ----
    float me = e[0];
#pragma unroll
    for (int r = 1; r < 8; ++r) me = fmaxf(me, e[r]);
    me = wave_reduce_max(me);

    float c = 0.f;
#pragma unroll
    for (int r = 0; r < 8; ++r) {
      float tl = q[r] * __expf(e[r] - me);
      v[r] = tl;
      c = fmaxf(c, tl);
    }
    c = wave_reduce_max(c);
    const float rinv = __builtin_amdgcn_rcpf(c);
#pragma unroll
    for (int r = 0; r < 8; ++r) v[r] *= rinv;

    if (accumulate) zacc += (double)(__logf(c) + me);
  };

  for (; t < tstart; ++t) step(t, false);  // burn-in (discard normalizers)
  for (; t < tend; ++t) step(t, true);     // accumulate log c_t

  if (chunk == NCHUNK - 1) {
    float s = 0.f;
#pragma unroll
    for (int r = 0; r < 8; ++r) s += v[r];
    s = wave_reduce_sum(s);
    zacc += (double)__logf(s);
  }

  if (l == 0) atomicAdd(accum, zacc);
}

__global__ void zero_acc_kernel(double* acc) {
  if (threadIdx.x == 0) *acc = 0.0;
}
__global__ void finalize_kernel(const double* __restrict__ acc,
                                float* __restrict__ out) {
  if (threadIdx.x == 0) out[0] = (float)(*acc);
}

extern "C" void kernel_launch(void* const* d_in, const int* in_sizes, int n_in,
                              void* d_out, int out_size, void* d_ws, size_t ws_size,
                              hipStream_t stream) {
  const int*   x     = (const int*)d_in[0];
  const float* lam0  = (const float*)d_in[1];
  const float* lam1  = (const float*)d_in[2];
  const float* lam2  = (const float*)d_in[3];
  const float* logA0 = (const float*)d_in[4];
  const float* logA1 = (const float*)d_in[5];
  const float* logA2 = (const float*)d_in[6];
  const float* logp0 = (const float*)d_in[7];
  const float* logp1 = (const float*)d_in[8];
  const float* logp2 = (const float*)d_in[9];
  double* acc = (double*)d_ws;
  float*  out = (float*)d_out;

  zero_acc_kernel<<<1, 64, 0, stream>>>(acc);
  hmm_fwd_chunk<<<NCHUNK, 64, 0, stream>>>(x, lam0, lam1, lam2,
                                           logA0, logA1, logA2,
                                           logp0, logp1, logp2, acc);
  finalize_kernel<<<1, 64, 0, stream>>>(acc, out);
}